// Round 2
// baseline (92.625 us; speedup 1.0000x reference)
//
#include <hip/hip_runtime.h>

// Problem constants (B,T,H,D,M) = (2, 2048, 8, 64, 64), fp32 in/out.
#define BB 2
#define TT 2048
#define HH 8
#define DD 64
#define CC 256           // chunks over T
#define TC (TT / CC)     // 8 timesteps per chunk (= 4 segs x 2 iters)
#define STRIDE (HH * DD) // 512 floats between consecutive timesteps
#define NBH (BB * HH)    // 16

__device__ __forceinline__ float feat(float x) {
    // elu(x) + 1 = x+1 (x>0) else exp(x)
    return x > 0.f ? x + 1.f : __expf(x);
}

// Lane map: g = lane&15 -> d-group (d = 4g..4g+3), seg = lane>>4 -> timestep
// within group-of-4. One wave float4-load = 4 timesteps x 64 d = 1 KB.

// Kernel 1: per (b,h,c) chunk sums of feat(k) over time. One wave per chunk.
__global__ void __launch_bounds__(64)
chunk_sums_kernel(const float* __restrict__ k, float* __restrict__ ws) {
    const int idx  = blockIdx.x;              // (b*H + h)*CC + c
    const int c    = idx & (CC - 1);
    const int h    = (idx >> 8) & (HH - 1);
    const int b    = idx >> 11;
    const int lane = threadIdx.x;
    const int g    = lane & 15;
    const int seg  = lane >> 4;

    const size_t off0 = (((size_t)b * TT + c * TC + seg) * HH + h) * DD + g * 4;
    const float4 k0 = *(const float4*)(k + off0);
    const float4 k1 = *(const float4*)(k + off0 + (size_t)4 * STRIDE);

    float4 s;
    s.x = feat(k0.x) + feat(k1.x);
    s.y = feat(k0.y) + feat(k1.y);
    s.z = feat(k0.z) + feat(k1.z);
    s.w = feat(k0.w) + feat(k1.w);

    // reduce over the 4 segments (lanes ^16, ^32)
    s.x += __shfl_xor(s.x, 16, 64); s.y += __shfl_xor(s.y, 16, 64);
    s.z += __shfl_xor(s.z, 16, 64); s.w += __shfl_xor(s.w, 16, 64);
    s.x += __shfl_xor(s.x, 32, 64); s.y += __shfl_xor(s.y, 32, 64);
    s.z += __shfl_xor(s.z, 32, 64); s.w += __shfl_xor(s.w, 32, 64);

    if (seg == 0)
        *(float4*)(ws + (size_t)idx * DD + g * 4) = s;
}

// Kernel 2: fused lookback-prefix + main compute. One wave per (b,h,c) chunk.
__global__ void __launch_bounds__(64)
linattn_kernel(const float* __restrict__ q, const float* __restrict__ k,
               const float* __restrict__ v, const float* __restrict__ ws,
               float* __restrict__ out) {
    const int idx  = blockIdx.x;
    const int c    = idx & (CC - 1);
    const int h    = (idx >> 8) & (HH - 1);
    const int b    = idx >> 11;
    const int lane = threadIdx.x;
    const int g    = lane & 15;
    const int seg  = lane >> 4;

    // lane's timesteps: t0 = c*TC + seg (iter 0), t0+4 (iter 1); d = 4g..4g+3
    const size_t off0 = (((size_t)b * TT + c * TC + seg) * HH + h) * DD + g * 4;
    const size_t off1 = off0 + (size_t)4 * STRIDE;

    // Issue all HBM loads first (independent; overlap with the L2 lookback).
    float4 kf0 = *(const float4*)(k + off0);
    float4 kf1 = *(const float4*)(k + off1);
    float4 qf0 = *(const float4*)(q + off0);
    float4 qf1 = *(const float4*)(q + off1);
    const float4 vv0 = *(const float4*)(v + off0);
    const float4 vv1 = *(const float4*)(v + off1);

    // Exclusive chunk carry: direct lookback over predecessors' chunk sums
    // (L2-resident: 64 KB per (b,h)). Each seg strides by 4 chunks, then
    // butterfly-reduce across segs so every lane holds carry for its 4 d's.
    const float* wsg = ws + (size_t)(idx - c) * DD + g * 4;
    float4 carry = make_float4(0.f, 0.f, 0.f, 0.f);
    for (int cp = seg; cp < c; cp += 4) {
        const float4 t = *(const float4*)(wsg + (size_t)cp * DD);
        carry.x += t.x; carry.y += t.y; carry.z += t.z; carry.w += t.w;
    }
    carry.x += __shfl_xor(carry.x, 16, 64); carry.y += __shfl_xor(carry.y, 16, 64);
    carry.z += __shfl_xor(carry.z, 16, 64); carry.w += __shfl_xor(carry.w, 16, 64);
    carry.x += __shfl_xor(carry.x, 32, 64); carry.y += __shfl_xor(carry.y, 32, 64);
    carry.z += __shfl_xor(carry.z, 32, 64); carry.w += __shfl_xor(carry.w, 32, 64);

    kf0.x = feat(kf0.x); kf0.y = feat(kf0.y); kf0.z = feat(kf0.z); kf0.w = feat(kf0.w);
    kf1.x = feat(kf1.x); kf1.y = feat(kf1.y); kf1.z = feat(kf1.z); kf1.w = feat(kf1.w);
    qf0.x = feat(qf0.x); qf0.y = feat(qf0.y); qf0.z = feat(qf0.z); qf0.w = feat(qf0.w);
    qf1.x = feat(qf1.x); qf1.y = feat(qf1.y); qf1.z = feat(qf1.z); qf1.w = feat(qf1.w);

    // ---- time cumsum per d: seg-inclusive scans of kf0/kf1 (Hillis-Steele o=16,32)
    float4 i0 = kf0, i1 = kf1;
    {
        float u;
        u = __shfl_up(i0.x, 16, 64); if (seg >= 1) i0.x += u;
        u = __shfl_up(i0.y, 16, 64); if (seg >= 1) i0.y += u;
        u = __shfl_up(i0.z, 16, 64); if (seg >= 1) i0.z += u;
        u = __shfl_up(i0.w, 16, 64); if (seg >= 1) i0.w += u;
        u = __shfl_up(i1.x, 16, 64); if (seg >= 1) i1.x += u;
        u = __shfl_up(i1.y, 16, 64); if (seg >= 1) i1.y += u;
        u = __shfl_up(i1.z, 16, 64); if (seg >= 1) i1.z += u;
        u = __shfl_up(i1.w, 16, 64); if (seg >= 1) i1.w += u;
        u = __shfl_up(i0.x, 32, 64); if (seg >= 2) i0.x += u;
        u = __shfl_up(i0.y, 32, 64); if (seg >= 2) i0.y += u;
        u = __shfl_up(i0.z, 32, 64); if (seg >= 2) i0.z += u;
        u = __shfl_up(i0.w, 32, 64); if (seg >= 2) i0.w += u;
        u = __shfl_up(i1.x, 32, 64); if (seg >= 2) i1.x += u;
        u = __shfl_up(i1.y, 32, 64); if (seg >= 2) i1.y += u;
        u = __shfl_up(i1.z, 32, 64); if (seg >= 2) i1.z += u;
        u = __shfl_up(i1.w, 32, 64); if (seg >= 2) i1.w += u;
    }
    // S0[d] = chunk-first-half total = i0 at seg=3 (lane 48+g), broadcast
    float4 S0;
    S0.x = __shfl(i0.x, 48 + g, 64);
    S0.y = __shfl(i0.y, 48 + g, 64);
    S0.z = __shfl(i0.z, 48 + g, 64);
    S0.w = __shfl(i0.w, 48 + g, 64);

    float4 run0, run1;   // inclusive time-cumsum of feat(k) per d
    run0.x = carry.x + i0.x; run0.y = carry.y + i0.y;
    run0.z = carry.z + i0.z; run0.w = carry.w + i0.w;
    run1.x = carry.x + S0.x + i1.x; run1.y = carry.y + S0.y + i1.y;
    run1.z = carry.z + S0.z + i1.z; run1.w = carry.w + S0.w + i1.w;

    // ---- d-prefix (inclusive over d) per timestep: in-lane prefix + group scan
    float4 p0, p1;
    p0.x = kf0.x; p0.y = p0.x + kf0.y; p0.z = p0.y + kf0.z; p0.w = p0.z + kf0.w;
    p1.x = kf1.x; p1.y = p1.x + kf1.y; p1.z = p1.y + kf1.z; p1.w = p1.z + kf1.w;
    float c0 = p0.w, c1 = p1.w;
    #pragma unroll
    for (int o = 1; o <= 8; o <<= 1) {
        float u0 = __shfl_up(c0, o, 16);
        float u1 = __shfl_up(c1, o, 16);
        if (g >= o) { c0 += u0; c1 += u1; }
    }
    const float e0 = c0 - p0.w;   // exclusive d-prefix entering this lane
    const float e1 = c1 - p1.w;

    // ---- reductions over d: s1 = qf.(d-prefix), s2 = qf.run (per timestep)
    const float sq0 = qf0.x + qf0.y + qf0.z + qf0.w;
    const float sq1 = qf1.x + qf1.y + qf1.z + qf1.w;
    float s1_0 = qf0.x * p0.x + qf0.y * p0.y + qf0.z * p0.z + qf0.w * p0.w + e0 * sq0;
    float s2_0 = qf0.x * run0.x + qf0.y * run0.y + qf0.z * run0.z + qf0.w * run0.w;
    float s1_1 = qf1.x * p1.x + qf1.y * p1.y + qf1.z * p1.z + qf1.w * p1.w + e1 * sq1;
    float s2_1 = qf1.x * run1.x + qf1.y * run1.y + qf1.z * run1.z + qf1.w * run1.w;
    #pragma unroll
    for (int o = 1; o <= 8; o <<= 1) {
        s1_0 += __shfl_xor(s1_0, o, 64);
        s2_0 += __shfl_xor(s2_0, o, 64);
        s1_1 += __shfl_xor(s1_1, o, 64);
        s2_1 += __shfl_xor(s2_1, o, 64);
    }

    const float r0 = s1_0 * __builtin_amdgcn_rcpf(s2_0);
    const float r1 = s1_1 * __builtin_amdgcn_rcpf(s2_1);
    float4 o0, o1;
    o0.x = vv0.x * r0; o0.y = vv0.y * r0; o0.z = vv0.z * r0; o0.w = vv0.w * r0;
    o1.x = vv1.x * r1; o1.y = vv1.y * r1; o1.z = vv1.z * r1; o1.w = vv1.w * r1;
    *(float4*)(out + off0) = o0;
    *(float4*)(out + off1) = o1;
}

extern "C" void kernel_launch(void* const* d_in, const int* in_sizes, int n_in,
                              void* d_out, int out_size, void* d_ws, size_t ws_size,
                              hipStream_t stream) {
    const float* q = (const float*)d_in[0];
    const float* k = (const float*)d_in[1];
    const float* v = (const float*)d_in[2];
    float* out = (float*)d_out;
    float* ws  = (float*)d_ws;            // needs B*H*CC*DD*4 = 1 MB

    const int nblk = BB * HH * CC;        // 4096
    chunk_sums_kernel<<<nblk, 64, 0, stream>>>(k, ws);
    linattn_kernel<<<nblk, 64, 0, stream>>>(q, k, v, ws, out);
}